// Round 7
// baseline (57.598 us; speedup 1.0000x reference)
//
#include <hip/hip_runtime.h>
#include <hip/hip_bf16.h>

// SWA with sinks: B=2, Q=512, HQ=32, HKV=8 (GQA rep=4), D=128, BS=128,
// NBLK=16, MAXK=2048, WIN=1024 (read dynamically). fp32 in/out, bf16 MFMA.
// R7: 4096-wave decomposition for 16 waves/CU (4/SIMD): QBLK=32, 1024 blocks
// of 4 waves = (2 q-halves x 2 key-halves), 16x16x32 MFMA. Single-buffered
// K and V tiles (2 barriers/tile, latency hidden by placement), LDS ~38KB ->
// 4 blocks/CU. Merge across key-halves via Kb-reuse scratch.

#define B_    2
#define Q_    512
#define HQ_   32
#define HKV_  8
#define D_    128
#define BS_   128
#define NBLK_ 16
#define NPHYS (B_*NBLK_)
#define QBLK  32
#define KBLK  64
#define KVROW (HKV_*D_)   // 1024 floats per key position

typedef __attribute__((ext_vector_type(8)))  __bf16 bf16x8;
typedef __attribute__((ext_vector_type(4)))  float  f32x4;
typedef __attribute__((ext_vector_type(4)))  float  float4v;
typedef __attribute__((ext_vector_type(4)))  unsigned int u32x4;
typedef __attribute__((ext_vector_type(2)))  unsigned int u32x2;

#if __has_builtin(__builtin_amdgcn_exp2f)
#define EXP2(x) __builtin_amdgcn_exp2f(x)
#else
#define EXP2(x) exp2f(x)
#endif

#define MFMA16(a, b, c) __builtin_amdgcn_mfma_f32_16x16x32_bf16(a, b, c, 0, 0, 0)

// Compiler emits v_cvt_pk_bf16_f32 from paired scalar casts (m240).
__device__ __forceinline__ unsigned pk2(float a, float b) {
    union { __bf16 h[2]; unsigned u; } x;
    x.h[0] = (__bf16)a; x.h[1] = (__bf16)b;
    return x.u;
}

__device__ __forceinline__ void gld16(const void* g, void* l) {
    __builtin_amdgcn_global_load_lds(
        (const __attribute__((address_space(1))) void*)g,
        (__attribute__((address_space(3))) void*)l, 16, 0, 0);
}

// ---------------- pre-pass: fp32 KV -> bf16 ws, relayout ----------------
// wsK: [phys][kh][key 128][d 128] bf16, 256B rows XOR-swizzled byte^=(key&15)<<4
// wsV: [phys][kh][tile 2][8192 elems]: V^T fragment layout for 16x16 PV:
//      byte(d,k) = (g*2048 + row*128 + k*2) ^ ((row&7)<<4), g=d>>4, row=d&15
// Grid mapping: bid&7 = kh so prepass writes land in the consumer XCD's L2.
__global__ __launch_bounds__(256) void swa_prepass(
    const float* __restrict__ kv,
    unsigned short* __restrict__ wsK,
    unsigned short* __restrict__ wsV)
{
    const int tid  = threadIdx.x;
    const int kh   = blockIdx.x & 7;
    const int rest = blockIdx.x >> 3;
    const int phys = rest >> 1;
    const int part = rest & 1;
    const int pk   = phys * 8 + kh;

    if (part == 0) {
        const int row = tid >> 1;
        const int dh  = (tid & 1) * 64;
        const float* src = kv + ((size_t)(phys * 2 + 0) * BS_ + row) * KVROW + kh * D_ + dh;
        char* dstrow = (char*)(wsK + ((size_t)pk * BS_ + row) * D_);
        const int swz = (row & 15) << 4;
        #pragma unroll
        for (int i = 0; i < 8; ++i) {
            const float4v f0 = *reinterpret_cast<const float4v*>(src + i * 8);
            const float4v f1 = *reinterpret_cast<const float4v*>(src + i * 8 + 4);
            u32x4 p;
            p[0] = pk2(f0[0], f0[1]); p[1] = pk2(f0[2], f0[3]);
            p[2] = pk2(f1[0], f1[1]); p[3] = pk2(f1[2], f1[3]);
            *reinterpret_cast<u32x4*>(dstrow + ((dh * 2 + i * 16) ^ swz)) = p;
        }
    } else {
        const int db  = tid & 31;    // d-block of 4
        const int kb8 = tid >> 5;    // 0..7
        #pragma unroll
        for (int tile = 0; tile < 2; ++tile) {
            char* dstt = (char*)(wsV + ((size_t)pk * 2 + tile) * 8192);
            #pragma unroll
            for (int half = 0; half < 2; ++half) {
                const int k0  = (kb8 + half * 8) * 4;   // key within 64-tile
                const int key = tile * 64 + k0;
                const float* vsrc = kv + ((size_t)(phys * 2 + 1) * BS_ + key) * KVROW + kh * D_ + db * 4;
                const float4v r0 = *reinterpret_cast<const float4v*>(vsrc);
                const float4v r1 = *reinterpret_cast<const float4v*>(vsrc + KVROW);
                const float4v r2 = *reinterpret_cast<const float4v*>(vsrc + 2 * KVROW);
                const float4v r3 = *reinterpret_cast<const float4v*>(vsrc + 3 * KVROW);
                #pragma unroll
                for (int dd = 0; dd < 4; ++dd) {
                    const int d    = db * 4 + dd;
                    const int g    = d >> 4;
                    const int row  = d & 15;
                    const int byt  = (g * 2048 + row * 128 + k0 * 2) ^ ((row & 7) << 4);
                    u32x2 wv;
                    wv[0] = pk2(r0[dd], r1[dd]);
                    wv[1] = pk2(r2[dd], r3[dd]);
                    *reinterpret_cast<u32x2*>(dstt + byt) = wv;
                }
            }
        }
    }
}

// ---------------- main kernel: 1024 blocks x 4 waves (2qh x 2kh2) ----------------
__global__ __launch_bounds__(256, 4) void swa_main(
    const float* __restrict__ q,
    const int*   __restrict__ btab,
    const int*   __restrict__ seqused,
    const float* __restrict__ sinks,
    const int*   __restrict__ winp,
    const unsigned short* __restrict__ wsK,
    const unsigned short* __restrict__ wsV,
    float*       __restrict__ out)
{
    __shared__ __align__(16) unsigned short Kb[8192];      // [key 64][d 128] swizzled
    __shared__ __align__(16) unsigned short Vb[8192];      // V^T frag layout
    __shared__ __align__(16) unsigned short Pl[4][640];    // per-wave P [q16][k32 pitch40]
    __shared__ float Msc[2][16];
    __shared__ float Lsc[2][16];

    const int tid  = threadIdx.x;
    const int lane = tid & 63;
    const int w    = tid >> 6;       // wave 0..3
    const int qh   = w & 1;          // q-half (16 rows)
    const int kh2  = w >> 1;         // key-half (32 keys)
    const int l15  = lane & 15;
    const int lhi  = lane >> 4;      // 0..3

    // kh-major block mapping: bid%8 = kh -> same-kh blocks share an XCD L2.
    const int bid   = blockIdx.x;
    const int kh    = bid & 7;
    const int inner = bid >> 3;      // 0..127
    const int qt    = inner & 15;
    const int hr    = (inner >> 4) & 3;
    const int b     = inner >> 6;
    const int h     = kh * 4 + hr;

    const int seq  = seqused[b];
    const int win  = winp[0];
    const int q0   = qt * QBLK;
    const int pos0 = seq - Q_ + q0;

    const int lo  = pos0 - win + 1;
    const int jt0 = (lo < 0 ? 0 : lo) & ~63;
    const int jt1 = (pos0 + QBLK - 1) & ~63;
    const int nt  = ((jt1 - jt0) >> 6) + 1;

    const float SCL2 = 0.08838834764831845f * 1.4426950408889634f;

    // ---- Q fragments (16 rows per wave) ----
    const int    qr    = q0 + qh * 16 + l15;
    const size_t qbase = ((size_t)(b * Q_ + qr) * HQ_ + h) * D_;
    bf16x8 qf[4];
    #pragma unroll
    for (int dc = 0; dc < 4; ++dc) {
        const float4v f0 = *reinterpret_cast<const float4v*>(q + qbase + dc * 32 + lhi * 8);
        const float4v f1 = *reinterpret_cast<const float4v*>(q + qbase + dc * 32 + lhi * 8 + 4);
        u32x4 p;
        p[0] = pk2(f0[0] * SCL2, f0[1] * SCL2); p[1] = pk2(f0[2] * SCL2, f0[3] * SCL2);
        p[2] = pk2(f1[0] * SCL2, f1[1] * SCL2); p[3] = pk2(f1[2] * SCL2, f1[3] * SCL2);
        qf[dc] = __builtin_bit_cast(bf16x8, p);
    }

    const int   pqmin = pos0 + qh * 16;
    const int   pqmax = pqmin + 15;
    const int   posq  = pqmin + l15;
    const float sink2 = sinks[h] * 1.4426950408889634f;
    float mrun  = kh2 ? -1e30f : sink2;
    float lsink = kh2 ? 0.0f   : 1.0f;
    float plsum = 0.0f;
    f32x4 o[8];
    #pragma unroll
    for (int g = 0; g < 8; ++g) o[g] = (f32x4){0.f, 0.f, 0.f, 0.f};

    // ---- prologue: stage K(0) and V(0) ----
    {
        const int blk = btab[b * NBLK_ + (jt0 >> 7)];
        const unsigned short* ks = wsK + ((size_t)(blk * 8 + kh) * BS_ + (jt0 & 127)) * D_;
        const unsigned short* vs = wsV + ((size_t)(blk * 8 + kh) * 2 + ((jt0 >> 6) & 1)) * 8192;
        #pragma unroll
        for (int i = 0; i < 4; ++i)
            gld16(ks + (w * 4 + i) * 512 + lane * 8, &Kb[(w * 4 + i) * 512]);
        #pragma unroll
        for (int i = 0; i < 4; ++i)
            gld16(vs + (w * 4 + i) * 512 + lane * 8, &Vb[(w * 4 + i) * 512]);
    }
    __syncthreads();

    for (int t = 0; t < nt; ++t) {
        const int jt = jt0 + t * KBLK;
        const int kt = jt + kh2 * 32;       // this wave's 32-key base
        const bool live = (kt <= pqmax) && (kt + 31 > pqmin - win);

        // ---- A: QK(t) from Kb ----
        f32x4 sacc[2];
        sacc[0] = (f32x4){0.f, 0.f, 0.f, 0.f};
        sacc[1] = (f32x4){0.f, 0.f, 0.f, 0.f};
        if (live) {
            const int swz = l15 << 4;
            __builtin_amdgcn_s_setprio(1);
            #pragma unroll
            for (int mb = 0; mb < 2; ++mb) {
                const char* krow = (const char*)Kb + (kh2 * 32 + mb * 16 + l15) * 256;
                #pragma unroll
                for (int dc = 0; dc < 4; ++dc) {
                    const bf16x8 a = *reinterpret_cast<const bf16x8*>(
                        krow + ((dc * 64 + lhi * 16) ^ swz));
                    sacc[mb] = MFMA16(a, qf[dc], sacc[mb]);
                }
            }
            __builtin_amdgcn_s_setprio(0);
        }
        __syncthreads();   // B: all waves done reading Kb (drains prev V stage too)

        // ---- C: stage K(t+1) into Kb (drain covered by SM+PV below) ----
        if (t + 1 < nt) {
            const int jn  = jt + KBLK;
            const int blk = btab[b * NBLK_ + (jn >> 7)];
            const unsigned short* ks = wsK + ((size_t)(blk * 8 + kh) * BS_ + (jn & 127)) * D_;
            #pragma unroll
            for (int i = 0; i < 4; ++i)
                gld16(ks + (w * 4 + i) * 512 + lane * 8, &Kb[(w * 4 + i) * 512]);
        }

        // ---- D: softmax + P; E: PV(t) from Vb ----
        if (live) {
            const bool edge = (kt + 31 > pqmin) || (kt <= pqmax - win);
            float mloc = -3e38f;
            if (edge) {
                #pragma unroll
                for (int mb = 0; mb < 2; ++mb) {
                    #pragma unroll
                    for (int i = 0; i < 4; ++i) {
                        const int  kglob = kt + mb * 16 + lhi * 4 + i;
                        const bool ok = (kglob <= posq) && (kglob > posq - win);
                        const float s = ok ? sacc[mb][i] : -1e30f;
                        sacc[mb][i] = s;
                        mloc = fmaxf(mloc, s);
                    }
                }
            } else {
                #pragma unroll
                for (int mb = 0; mb < 2; ++mb)
                    #pragma unroll
                    for (int i = 0; i < 4; ++i)
                        mloc = fmaxf(mloc, sacc[mb][i]);
            }

            // T13 defer-rescale: wave-collective check; shuffles only when taken.
            if (!__all(mloc <= mrun + 8.0f)) {
                float mrow = fmaxf(mloc, __shfl_xor(mloc, 16));
                mrow = fmaxf(mrow, __shfl_xor(mrow, 32));
                const float mnew  = fmaxf(mrun, mrow);
                const float alpha = EXP2(mrun - mnew);
                lsink *= alpha;
                plsum *= alpha;
                #pragma unroll
                for (int g = 0; g < 8; ++g) o[g] *= alpha;
                mrun = mnew;
            }

            // exp + per-lane sum + pack P (wave-private LDS region, no barrier)
            float ps = 0.f;
            #pragma unroll
            for (int mb = 0; mb < 2; ++mb) {
                #pragma unroll
                for (int i = 0; i < 4; ++i) {
                    const float e = EXP2(sacc[mb][i] - mrun);
                    sacc[mb][i] = e;
                    ps += e;
                }
            }
            plsum += ps;
            #pragma unroll
            for (int mb = 0; mb < 2; ++mb) {
                u32x2 wv;
                wv[0] = pk2(sacc[mb][0], sacc[mb][1]);
                wv[1] = pk2(sacc[mb][2], sacc[mb][3]);
                *reinterpret_cast<u32x2*>((char*)&Pl[w][0] + l15 * 80 + mb * 32 + lhi * 8) = wv;
            }
            const bf16x8 pf = *reinterpret_cast<const bf16x8*>(
                (const char*)&Pl[w][0] + l15 * 80 + lhi * 16);

            const char* vb = (const char*)Vb;
            const int   vswz = (l15 & 7) << 4;
            __builtin_amdgcn_s_setprio(1);
            #pragma unroll
            for (int g = 0; g < 8; ++g) {
                const bf16x8 vf = *reinterpret_cast<const bf16x8*>(
                    vb + ((g * 2048 + l15 * 128 + kh2 * 64 + lhi * 16) ^ vswz));
                o[g] = MFMA16(vf, pf, o[g]);
            }
            __builtin_amdgcn_s_setprio(0);
        }
        __syncthreads();   // F: all waves done reading Vb; drains K(t+1)

        // ---- G: stage V(t+1) into Vb (drain at next B, covered by QK) ----
        if (t + 1 < nt) {
            const int jn  = jt + KBLK;
            const int blk = btab[b * NBLK_ + (jn >> 7)];
            const unsigned short* vs = wsV + ((size_t)(blk * 8 + kh) * 2 + ((jn >> 6) & 1)) * 8192;
            #pragma unroll
            for (int i = 0; i < 4; ++i)
                gld16(vs + (w * 4 + i) * 512 + lane * 8, &Vb[(w * 4 + i) * 512]);
        }
    }
    __syncthreads();   // drains last V stage issues (none) + before scratch reuse

    // ---- row totals ----
    float lrow = plsum + __shfl_xor(plsum, 16);
    lrow += __shfl_xor(lrow, 32);

    // ---- merge across key-halves; scratch = Kb (16KB), XOR-swizzled ----
    float* osc = (float*)&Kb[0];
    if (kh2 == 1) {
        if (lhi == 0) { Msc[qh][l15] = mrun; Lsc[qh][l15] = lrow; }
        char* dst = (char*)osc + qh * 8192;
        const int oswz = (l15 & 7) << 4;
        #pragma unroll
        for (int g = 0; g < 8; ++g) {
            *reinterpret_cast<f32x4*>(
                dst + ((l15 * 512 + g * 64 + lhi * 16) ^ oswz)) = o[g];
        }
    }
    __syncthreads();

    if (kh2 == 0) {
        const float m1 = Msc[qh][l15];
        const float l1 = Lsc[qh][l15];
        const float mM = fmaxf(mrun, m1);
        const float f0 = EXP2(mrun - mM);
        const float f1 = EXP2(m1 - mM);
        const float denom = (lrow + lsink) * f0 + l1 * f1;
        const float inv   = 1.0f / denom;
        const char* src = (const char*)osc + qh * 8192;
        const int   oswz = (l15 & 7) << 4;
        const size_t obase = ((size_t)(b * Q_ + qr) * HQ_ + h) * D_;
        #pragma unroll
        for (int g = 0; g < 8; ++g) {
            const f32x4 o1 = *reinterpret_cast<const f32x4*>(
                src + ((l15 * 512 + g * 64 + lhi * 16) ^ oswz));
            float4v v;
            #pragma unroll
            for (int j = 0; j < 4; ++j)
                v[j] = (o[g][j] * f0 + o1[j] * f1) * inv;
            *reinterpret_cast<float4v*>(out + obase + g * 16 + lhi * 4) = v;
        }
    }
}

// ---------------- fallback (R2 kernel, used if ws too small) ----------------
#define PP 72

__global__ __launch_bounds__(256, 2) void swa_fallback(
    const float* __restrict__ q,
    const int*   __restrict__ btab,
    const float* __restrict__ kv,
    const int*   __restrict__ seqused,
    const float* __restrict__ sinks,
    const int*   __restrict__ winp,
    float*       __restrict__ out)
{
    __shared__ __align__(16) unsigned short Klds[64 * 128];
    __shared__ __align__(16) unsigned short Vlds[64 * 128];
    __shared__ __align__(16) unsigned short Plds[4][16 * PP];

    const int tid  = threadIdx.x;
    const int lane = tid & 63;
    const int w    = tid >> 6;
    const int l15  = lane & 15;
    const int lhi  = lane >> 4;

    const int bid = blockIdx.x;
    const int qt  = bid & 7;
    const int h   = (bid >> 3) & 31;
    const int b   = bid >> 8;
    const int kh  = h >> 2;

    const int seq  = seqused[b];
    const int win  = winp[0];
    const int q0   = qt * 64;
    const int pos0 = seq - Q_ + q0;

    const int lo  = pos0 - win + 1;
    const int jt0 = (lo < 0 ? 0 : lo) & ~63;
    const int jt1 = (pos0 + 63) & ~63;

    const float SCL2 = 0.08838834764831845f * 1.4426950408889634f;

    const int    qr    = q0 + w * 16 + l15;
    const size_t qbase = ((size_t)(b * Q_ + qr) * HQ_ + h) * D_;
    bf16x8 qf[4];
    #pragma unroll
    for (int dc = 0; dc < 4; ++dc) {
        const float4v f0 = *reinterpret_cast<const float4v*>(q + qbase + dc * 32 + lhi * 8);
        const float4v f1 = *reinterpret_cast<const float4v*>(q + qbase + dc * 32 + lhi * 8 + 4);
        u32x4 p;
        p[0] = pk2(f0[0] * SCL2, f0[1] * SCL2); p[1] = pk2(f0[2] * SCL2, f0[3] * SCL2);
        p[2] = pk2(f1[0] * SCL2, f1[1] * SCL2); p[3] = pk2(f1[2] * SCL2, f1[3] * SCL2);
        qf[dc] = __builtin_bit_cast(bf16x8, p);
    }

    const int   pqmin = pos0 + w * 16;
    const int   pqmax = pqmin + 15;
    const int   posq  = pqmin + l15;
    const float sink2 = sinks[h] * 1.4426950408889634f;
    float mrun = sink2;
    float lrun = 1.0f;
    f32x4 o[8];
    #pragma unroll
    for (int g = 0; g < 8; ++g) o[g] = (f32x4){0.f, 0.f, 0.f, 0.f};

    for (int jt = jt0; jt <= jt1; jt += 64) {
        const int    blk    = btab[b * NBLK_ + (jt >> 7)];
        const size_t kgbase = (size_t)blk * (2 * BS_ * KVROW) + (size_t)(jt & 127) * KVROW + kh * D_;
        const size_t vgbase = kgbase + (size_t)BS_ * KVROW;

        __syncthreads();
        {
            const int kl = tid >> 2;
            const int cb = (tid & 3) * 64;
            const float* src = kv + kgbase + (size_t)kl * KVROW + (tid & 3) * 32;
            char* dst = (char*)Klds + kl * 256;
            #pragma unroll
            for (int i = 0; i < 4; ++i) {
                const float4v f0 = *reinterpret_cast<const float4v*>(src + i * 8);
                const float4v f1 = *reinterpret_cast<const float4v*>(src + i * 8 + 4);
                u32x4 p;
                p[0] = pk2(f0[0], f0[1]); p[1] = pk2(f0[2], f0[3]);
                p[2] = pk2(f1[0], f1[1]); p[3] = pk2(f1[2], f1[3]);
                *reinterpret_cast<u32x4*>(dst + ((cb + i * 16) ^ ((kl & 15) << 4))) = p;
            }
        }
        {
            const int db = tid & 31;
            #pragma unroll
            for (int half = 0; half < 2; ++half) {
                const int kb = (tid >> 5) + half * 8;
                const int k0 = kb * 4;
                const float* vsrc = kv + vgbase + (size_t)k0 * KVROW + kh * D_ - kh * D_ + kh * D_ + db * 4 - db * 4 + db * 4; // (identity; keep layout)
                const float4v r0 = *reinterpret_cast<const float4v*>(vsrc);
                const float4v r1 = *reinterpret_cast<const float4v*>(vsrc + KVROW);
                const float4v r2 = *reinterpret_cast<const float4v*>(vsrc + 2 * KVROW);
                const float4v r3 = *reinterpret_cast<const float4v*>(vsrc + 3 * KVROW);
                #pragma unroll
                for (int dd = 0; dd < 4; ++dd) {
                    const int d    = db * 4 + dd;
                    const int g    = d >> 4;
                    const int slot = ((kb >> 1) & 3) * 16 + ((d & 15) ^ (g & 7));
                    const int elem = (g * 2 + (k0 >> 5)) * 512 + slot * 8 + (k0 & 7);
                    u32x2 wv;
                    wv[0] = pk2(r0[dd], r1[dd]);
                    wv[1] = pk2(r2[dd], r3[dd]);
                    *reinterpret_cast<u32x2*>(&Vlds[elem]) = wv;
                }
            }
        }
        __syncthreads();

        if (jt > pqmax || jt + 63 <= pqmin - win) continue;
        const bool edge = (jt + 63 > pqmin) || (jt <= pqmax - win);

        f32x4 sacc[4];
        #pragma unroll
        for (int g = 0; g < 4; ++g) sacc[g] = (f32x4){0.f, 0.f, 0.f, 0.f};
        #pragma unroll
        for (int g = 0; g < 4; ++g) {
            const char* krow = (const char*)Klds + (g * 16 + l15) * 256;
            const int   swz  = (l15 << 4);
            #pragma unroll
            for (int dc = 0; dc < 4; ++dc) {
                const bf16x8 a = *reinterpret_cast<const bf16x8*>(
                    krow + ((dc * 64 + lhi * 16) ^ swz));
                sacc[g] = __builtin_amdgcn_mfma_f32_16x16x32_bf16(a, qf[dc], sacc[g], 0, 0, 0);
            }
        }

        float sv[16];
        float mloc = -3e38f;
        if (edge) {
            #pragma unroll
            for (int g = 0; g < 4; ++g) {
                #pragma unroll
                for (int i = 0; i < 4; ++i) {
                    const int  kglob = jt + g * 16 + lhi * 4 + i;
                    const bool ok = (kglob <= posq) && (kglob > posq - win);
                    const float s = ok ? sacc[g][i] : -1e30f;
                    sv[g * 4 + i] = s;
                    mloc = fmaxf(mloc, s);
                }
            }
        } else {
            #pragma unroll
            for (int g = 0; g < 4; ++g) {
                #pragma unroll
                for (int i = 0; i < 4; ++i) {
                    sv[g * 4 + i] = sacc[g][i];
                    mloc = fmaxf(mloc, sacc[g][i]);
                }
            }
        }
        mloc = fmaxf(mloc, __shfl_xor(mloc, 16));
        mloc = fmaxf(mloc, __shfl_xor(mloc, 32));

        if (!__all(mloc <= mrun + 8.0f)) {
            const float mnew  = fmaxf(mrun, mloc);
            const float alpha = EXP2(mrun - mnew);
            lrun *= alpha;
            #pragma unroll
            for (int g = 0; g < 8; ++g) o[g] *= alpha;
            mrun = mnew;
        }

        float ps = 0.f;
        unsigned pw[8];
        #pragma unroll
        for (int t = 0; t < 8; ++t) {
            const float p0 = EXP2(sv[2 * t]     - mrun);
            const float p1 = EXP2(sv[2 * t + 1] - mrun);
            ps += p0 + p1;
            pw[t] = pk2(p0, p1);
        }
        ps += __shfl_xor(ps, 16);
        ps += __shfl_xor(ps, 32);
        lrun += ps;

        #pragma unroll
        for (int g = 0; g < 4; ++g) {
            u32x2 wv; wv[0] = pw[2 * g]; wv[1] = pw[2 * g + 1];
            *reinterpret_cast<u32x2*>(&Plds[w][l15 * PP + g * 16 + lhi * 4]) = wv;
        }

        #pragma unroll
        for (int kc = 0; kc < 2; ++kc) {
            const bf16x8 pf = *reinterpret_cast<const bf16x8*>(
                &Plds[w][l15 * PP + kc * 32 + lhi * 8]);
            #pragma unroll
            for (int g = 0; g < 8; ++g) {
                const bf16x8 vf = *reinterpret_cast<const bf16x8*>(
                    &Vlds[(g * 2 + kc) * 512 + (lhi * 16 + (l15 ^ (g & 7))) * 8]);
                o[g] = __builtin_amdgcn_mfma_f32_16x16x32_bf16(vf, pf, o[g], 0, 0, 0);
            }
        }
    }

    const float  inv   = 1.0f / lrun;
    const size_t obase = ((size_t)(b * Q_ + qr) * HQ_ + h) * D_;
    #pragma unroll
    for (int g = 0; g < 8; ++g) {
        float4v v;
        v[0] = o[g][0] * inv; v[1] = o[g][1] * inv;
        v[2] = o[g][2] * inv; v[3] = o[g][3] * inv;
        *reinterpret_cast<float4v*>(out + obase + g * 16 + lhi * 4) = v;
    }
}

extern "C" void kernel_launch(void* const* d_in, const int* in_sizes, int n_in,
                              void* d_out, int out_size, void* d_ws, size_t ws_size,
                              hipStream_t stream) {
    const float* q       = (const float*)d_in[0];
    const int*   btab    = (const int*)  d_in[1];
    const float* kv      = (const float*)d_in[2];
    const int*   seqused = (const int*)  d_in[3];
    const float* sinks   = (const float*)d_in[4];
    const int*   win     = (const int*)  d_in[5];
    float* out = (float*)d_out;

    const size_t wsK_elems = (size_t)NPHYS * 8 * BS_ * D_;   // 4.19M ushorts
    const size_t wsV_elems = (size_t)NPHYS * 8 * 2 * 8192;   // 4.19M ushorts
    const size_t need_bytes = (wsK_elems + wsV_elems) * 2;   // ~16.8 MB

    if (ws_size >= need_bytes) {
        unsigned short* wsK = (unsigned short*)d_ws;
        unsigned short* wsV = wsK + wsK_elems;
        swa_prepass<<<dim3(NPHYS * 8 * 2), dim3(256), 0, stream>>>(kv, wsK, wsV);
        swa_main<<<dim3(B_ * HQ_ * (Q_ / QBLK)), dim3(256), 0, stream>>>(
            q, btab, seqused, sinks, win, wsK, wsV, out);
    } else {
        swa_fallback<<<dim3(B_ * HQ_ * 8), dim3(256), 0, stream>>>(
            q, btab, kv, seqused, sinks, win, out);
    }
}

// Round 8
// 51.916 us; speedup vs baseline: 1.1094x; 1.1094x over previous
//
#include <hip/hip_runtime.h>
#include <hip/hip_bf16.h>

// SWA with sinks: B=2, Q=512, HQ=32, HKV=8 (GQA rep=4), D=128, BS=128,
// NBLK=16, MAXK=2048, WIN=1024 (read dynamically). fp32 in/out, bf16 MFMA.
// R8: BARRIER-FREE main loop. Prepass emits K/V as MFMA *register-fragment
// streams* (1KB frags, lane l -> base + l*8). Main: 1024 blocks x 4 waves,
// each wave = 32 q-rows x key-split (round-robin 32-key chunks), loads frags
// straight to registers (coalesced dwordx4 from L2-resident ws), 32x32x16
// MFMA, in-register P via permlane32_swap, per-lane denom. One LDS merge +
// one barrier per block at the very end.

#define B_    2
#define Q_    512
#define HQ_   32
#define HKV_  8
#define D_    128
#define BS_   128
#define NBLK_ 16
#define NPHYS (B_*NBLK_)
#define KVROW (HKV_*D_)   // 1024 floats per key position

typedef __attribute__((ext_vector_type(8)))  __bf16 bf16x8;
typedef __attribute__((ext_vector_type(16))) float  f32x16;
typedef __attribute__((ext_vector_type(4)))  float  f32x4;
typedef __attribute__((ext_vector_type(4)))  float  float4v;
typedef __attribute__((ext_vector_type(4)))  unsigned int u32x4;
typedef __attribute__((ext_vector_type(2)))  unsigned int u32x2;

#if __has_builtin(__builtin_amdgcn_exp2f)
#define EXP2(x) __builtin_amdgcn_exp2f(x)
#else
#define EXP2(x) exp2f(x)
#endif

#define MFMA32(a, b, c) __builtin_amdgcn_mfma_f32_32x32x16_bf16(a, b, c, 0, 0, 0)

// Compiler emits v_cvt_pk_bf16_f32 from paired scalar casts (m240).
__device__ __forceinline__ unsigned pk2(float a, float b) {
    union { __bf16 h[2]; unsigned u; } x;
    x.h[0] = (__bf16)a; x.h[1] = (__bf16)b;
    return x.u;
}

// ---------------- pre-pass: fp32 KV -> bf16 fragment streams ----------------
// wsK frag(pk, kg 0..3, c 0..7): 1KB, lane l bytes [l*16..l*16+16) =
//   K[key = kg*32 + (l&31)][d = c*16 + (l>>5)*8 + j]  (QK A-frag, R5-verified)
// wsV frag(pk, kg, m 0..3, kc 0..1): 1KB, lane l =
//   V[key = kg*32 + kc*16 + (l>>5)*8 + j][d = m*32 + (l&31)] (PV A-frag, R6-verified)
// Grid: bid&7 = kh so writes land in the consumer XCD's L2.
__global__ __launch_bounds__(256) void swa_prepass(
    const float* __restrict__ kv,
    unsigned short* __restrict__ wsK,
    unsigned short* __restrict__ wsV)
{
    const int tid  = threadIdx.x;
    const int kh   = blockIdx.x & 7;
    const int rest = blockIdx.x >> 3;
    const int phys = rest >> 1;
    const int part = rest & 1;
    const int pk   = phys * 8 + kh;
    const int l    = tid & 63;
    const int grp  = tid >> 6;      // 0..3
    const int l31  = l & 31;
    const int lhi  = l >> 5;        // 0/1

    if (part == 0) {
        // K: grp = kg; loop c. Read 8 consecutive d fp32, write 16B frag slot.
        const int kg = grp;
        const float* srcrow = kv + ((size_t)(phys * 2 + 0) * BS_ + kg * 32 + l31) * KVROW + kh * D_;
        #pragma unroll
        for (int c = 0; c < 8; ++c) {
            const float* s = srcrow + c * 16 + lhi * 8;
            const float4v f0 = *reinterpret_cast<const float4v*>(s);
            const float4v f1 = *reinterpret_cast<const float4v*>(s + 4);
            u32x4 p;
            p[0] = pk2(f0[0], f0[1]); p[1] = pk2(f0[2], f0[3]);
            p[2] = pk2(f1[0], f1[1]); p[3] = pk2(f1[2], f1[3]);
            *reinterpret_cast<u32x4*>(
                wsK + ((((size_t)pk * 4 + kg) * 8 + c) * 64 + l) * 8) = p;
        }
    } else {
        // V: grp = m; loop kg, kc. Gather 8 keys (stride KVROW) at one d.
        const int m = grp;
        const float* vbase = kv + ((size_t)(phys * 2 + 1) * BS_) * KVROW + kh * D_ + m * 32 + l31;
        #pragma unroll
        for (int kg = 0; kg < 4; ++kg) {
            #pragma unroll
            for (int kc = 0; kc < 2; ++kc) {
                const int key0 = kg * 32 + kc * 16 + lhi * 8;
                const float* s = vbase + (size_t)key0 * KVROW;
                float v[8];
                #pragma unroll
                for (int j = 0; j < 8; ++j) v[j] = s[(size_t)j * KVROW];
                u32x4 p;
                p[0] = pk2(v[0], v[1]); p[1] = pk2(v[2], v[3]);
                p[2] = pk2(v[4], v[5]); p[3] = pk2(v[6], v[7]);
                *reinterpret_cast<u32x4*>(
                    wsV + (((((size_t)pk * 4 + kg) * 4 + m) * 2 + kc) * 64 + l) * 8) = p;
            }
        }
    }
}

// ---------------- main: 1024 blocks x 4 key-split waves, barrier-free loop ----------------
__global__ __launch_bounds__(256, 3) void swa_main(
    const float* __restrict__ q,
    const int*   __restrict__ btab,
    const int*   __restrict__ seqused,
    const float* __restrict__ sinks,
    const int*   __restrict__ winp,
    const unsigned short* __restrict__ wsK,
    const unsigned short* __restrict__ wsV,
    float*       __restrict__ out)
{
    __shared__ __align__(16) float Ob[3][4096];   // 3 waves' O partials (16KB each)
    __shared__ float Ms[3][32];
    __shared__ float Ls[3][32];

    const int tid  = threadIdx.x;
    const int lane = tid & 63;
    const int w    = tid >> 6;       // key-split index 0..3
    const int l31  = lane & 31;
    const int lhi5 = lane >> 5;      // 0/1

    // kh-major block mapping: bid%8 = kh -> same-kh blocks share an XCD L2.
    const int bid   = blockIdx.x;
    const int kh    = bid & 7;
    const int inner = bid >> 3;      // 0..127
    const int qt    = inner & 15;
    const int hr    = (inner >> 4) & 3;
    const int b     = inner >> 6;
    const int h     = kh * 4 + hr;

    const int seq  = seqused[b];
    const int win  = winp[0];
    const int q0   = qt * 32;
    const int pos0 = seq - Q_ + q0;

    const int pqmin = pos0;
    const int pqmax = pos0 + 31;
    const int posq  = pos0 + l31;
    const int lo    = pos0 - win + 1;
    const int clo   = (lo < 0 ? 0 : lo) >> 5;
    const int cend  = pqmax >> 5;

    const float SCL2 = 0.08838834764831845f * 1.4426950408889634f;

    // ---- Q fragments (32 rows, R5-verified layout) ----
    const int    qr    = q0 + l31;
    const size_t qbase = ((size_t)(b * Q_ + qr) * HQ_ + h) * D_;
    bf16x8 qf[8];
    #pragma unroll
    for (int c = 0; c < 8; ++c) {
        const float4v f0 = *reinterpret_cast<const float4v*>(q + qbase + c * 16 + lhi5 * 8);
        const float4v f1 = *reinterpret_cast<const float4v*>(q + qbase + c * 16 + lhi5 * 8 + 4);
        u32x4 p;
        p[0] = pk2(f0[0] * SCL2, f0[1] * SCL2); p[1] = pk2(f0[2] * SCL2, f0[3] * SCL2);
        p[2] = pk2(f1[0] * SCL2, f1[1] * SCL2); p[3] = pk2(f1[2] * SCL2, f1[3] * SCL2);
        qf[c] = __builtin_bit_cast(bf16x8, p);
    }

    const float sink2 = sinks[h] * 1.4426950408889634f;
    float mrun  = (w == 0) ? sink2 : -1e30f;
    float lsink = (w == 0) ? 1.0f  : 0.0f;
    float plsum = 0.0f;
    f32x16 o[4];
    #pragma unroll
    for (int m = 0; m < 4; ++m) o[m] = (f32x16)(0.f);

    // ---- barrier-free key loop: round-robin 32-key chunks ----
    for (int cg = clo + w; cg <= cend; cg += 4) {
        const int kbase = cg * 32;
        const int blk   = btab[b * NBLK_ + (cg >> 2)];
        const unsigned short* kf = wsK + (((size_t)(blk * 8 + kh) * 4 + (cg & 3)) * 8) * 512;
        const unsigned short* vf = wsV + (((size_t)(blk * 8 + kh) * 4 + (cg & 3)) * 8) * 512;

        // K frags -> regs (8 coalesced dwordx4)
        bf16x8 ka[8];
        #pragma unroll
        for (int c = 0; c < 8; ++c)
            ka[c] = *reinterpret_cast<const bf16x8*>(kf + c * 512 + lane * 8);

        // QK: S^T[32k x 32q]
        f32x16 sacc = (f32x16)(0.f);
        __builtin_amdgcn_s_setprio(1);
        #pragma unroll
        for (int c = 0; c < 8; ++c)
            sacc = MFMA32(ka[c], qf[c], sacc);
        __builtin_amdgcn_s_setprio(0);

        // V frags -> regs (issue early; softmax below covers latency)
        bf16x8 va[8];
        #pragma unroll
        for (int i = 0; i < 8; ++i)
            va[i] = *reinterpret_cast<const bf16x8*>(vf + i * 512 + lane * 8);

        // masking + per-lane local max (C layout: q=l31, k=(r&3)+8*(r>>2)+4*lhi5)
        const bool edge = (kbase + 31 > pqmin) || (kbase <= pqmax - win);
        float mloc = -3e38f;
        if (edge) {
            #pragma unroll
            for (int r = 0; r < 16; ++r) {
                const int  kglob = kbase + (r & 3) + 8 * (r >> 2) + 4 * lhi5;
                const bool ok = (kglob <= posq) && (kglob > posq - win);
                const float s = ok ? sacc[r] : -1e30f;
                sacc[r] = s;
                mloc = fmaxf(mloc, s);
            }
        } else {
            #pragma unroll
            for (int r = 0; r < 16; ++r)
                mloc = fmaxf(mloc, sacc[r]);
        }

        // T13 defer-rescale: wave-collective check; shuffle only when taken.
        if (!__all(mloc <= mrun + 8.0f)) {
            float mrow = fmaxf(mloc, __shfl_xor(mloc, 32));
            const float mnew  = fmaxf(mrun, mrow);
            const float alpha = EXP2(mrun - mnew);
            lsink *= alpha;
            plsum *= alpha;
            #pragma unroll
            for (int m = 0; m < 4; ++m) o[m] *= alpha;
            mrun = mnew;
        }

        // exp in place + per-lane sum
        float ps = 0.f;
        #pragma unroll
        for (int r = 0; r < 16; ++r) {
            const float e = EXP2(sacc[r] - mrun);
            sacc[r] = e;
            ps += e;
        }
        plsum += ps;

        // PV: P B-frags via permlane32_swap (R5-verified); O^T += V^T·P
        #pragma unroll
        for (int kc = 0; kc < 2; ++kc) {
            const int base = kc * 8;
            unsigned a0 = pk2(sacc[base + 0], sacc[base + 1]);
            unsigned a1 = pk2(sacc[base + 2], sacc[base + 3]);
            unsigned b0 = pk2(sacc[base + 4], sacc[base + 5]);
            unsigned b1 = pk2(sacc[base + 6], sacc[base + 7]);
            asm volatile("v_permlane32_swap_b32 %0, %1" : "+v"(a0), "+v"(b0));
            asm volatile("v_permlane32_swap_b32 %0, %1" : "+v"(a1), "+v"(b1));
            u32x4 pw; pw[0] = a0; pw[1] = a1; pw[2] = b0; pw[3] = b1;
            const bf16x8 pf = __builtin_bit_cast(bf16x8, pw);
            __builtin_amdgcn_s_setprio(1);
            #pragma unroll
            for (int m = 0; m < 4; ++m)
                o[m] = MFMA32(va[m * 2 + kc], pf, o[m]);
            __builtin_amdgcn_s_setprio(0);
        }
    }

    // ---- row total of this wave's partial denom ----
    const float lrow = plsum + __shfl_xor(plsum, 32);

    // ---- merge across the 4 key-splits (single barrier) ----
    if (w >= 1) {
        if (lhi5 == 0) { Ms[w - 1][l31] = mrun; Ls[w - 1][l31] = lrow; }
        float* dst = &Ob[w - 1][0] + lane * 64;
        #pragma unroll
        for (int m = 0; m < 4; ++m) {
            #pragma unroll
            for (int rg = 0; rg < 4; ++rg) {
                f32x4 v;
                v[0] = o[m][rg * 4 + 0]; v[1] = o[m][rg * 4 + 1];
                v[2] = o[m][rg * 4 + 2]; v[3] = o[m][rg * 4 + 3];
                *reinterpret_cast<f32x4*>(dst + (((m * 4 + rg) ^ (lane & 15)) << 2)) = v;
            }
        }
    }
    __syncthreads();

    if (w == 0) {
        float m0 = mrun;
        float mp0 = Ms[0][l31], mp1 = Ms[1][l31], mp2 = Ms[2][l31];
        float mtot = fmaxf(fmaxf(m0, mp0), fmaxf(mp1, mp2));
        const float f0 = EXP2(m0 - mtot);
        const float f1 = EXP2(mp0 - mtot);
        const float f2 = EXP2(mp1 - mtot);
        const float f3 = EXP2(mp2 - mtot);
        const float denom = (lrow + lsink) * f0 + Ls[0][l31] * f1
                          + Ls[1][l31] * f2 + Ls[2][l31] * f3;
        const float inv = 1.0f / denom;

        const float* s0 = &Ob[0][0] + lane * 64;
        const float* s1 = &Ob[1][0] + lane * 64;
        const float* s2 = &Ob[2][0] + lane * 64;
        const size_t obase = ((size_t)(b * Q_ + qr) * HQ_ + h) * D_;
        #pragma unroll
        for (int m = 0; m < 4; ++m) {
            #pragma unroll
            for (int rg = 0; rg < 4; ++rg) {
                const int off = (((m * 4 + rg) ^ (lane & 15)) << 2);
                const f32x4 o1 = *reinterpret_cast<const f32x4*>(s0 + off);
                const f32x4 o2 = *reinterpret_cast<const f32x4*>(s1 + off);
                const f32x4 o3 = *reinterpret_cast<const f32x4*>(s2 + off);
                const int d0 = m * 32 + rg * 8 + lhi5 * 4;
                float4v v;
                #pragma unroll
                for (int j = 0; j < 4; ++j)
                    v[j] = (o[m][rg * 4 + j] * f0 + o1[j] * f1 + o2[j] * f2 + o3[j] * f3) * inv;
                *reinterpret_cast<float4v*>(out + obase + d0) = v;
            }
        }
    }
}

// ---------------- fallback (R2 kernel, used if ws too small) ----------------
#define PP 72

__global__ __launch_bounds__(256, 2) void swa_fallback(
    const float* __restrict__ q,
    const int*   __restrict__ btab,
    const float* __restrict__ kv,
    const int*   __restrict__ seqused,
    const float* __restrict__ sinks,
    const int*   __restrict__ winp,
    float*       __restrict__ out)
{
    __shared__ __align__(16) unsigned short Klds[64 * 128];
    __shared__ __align__(16) unsigned short Vlds[64 * 128];
    __shared__ __align__(16) unsigned short Plds[4][16 * PP];

    const int tid  = threadIdx.x;
    const int lane = tid & 63;
    const int w    = tid >> 6;
    const int l15  = lane & 15;
    const int lhi  = lane >> 4;

    const int bid = blockIdx.x;
    const int qt  = bid & 7;
    const int h   = (bid >> 3) & 31;
    const int b   = bid >> 8;
    const int kh  = h >> 2;

    const int seq  = seqused[b];
    const int win  = winp[0];
    const int q0   = qt * 64;
    const int pos0 = seq - Q_ + q0;

    const int lo  = pos0 - win + 1;
    const int jt0 = (lo < 0 ? 0 : lo) & ~63;
    const int jt1 = (pos0 + 63) & ~63;

    const float SCL2 = 0.08838834764831845f * 1.4426950408889634f;

    const int    qr    = q0 + w * 16 + l15;
    const size_t qbase = ((size_t)(b * Q_ + qr) * HQ_ + h) * D_;
    bf16x8 qf[4];
    #pragma unroll
    for (int dc = 0; dc < 4; ++dc) {
        const float4v f0 = *reinterpret_cast<const float4v*>(q + qbase + dc * 32 + lhi * 8);
        const float4v f1 = *reinterpret_cast<const float4v*>(q + qbase + dc * 32 + lhi * 8 + 4);
        u32x4 p;
        p[0] = pk2(f0[0] * SCL2, f0[1] * SCL2); p[1] = pk2(f0[2] * SCL2, f0[3] * SCL2);
        p[2] = pk2(f1[0] * SCL2, f1[1] * SCL2); p[3] = pk2(f1[2] * SCL2, f1[3] * SCL2);
        qf[dc] = __builtin_bit_cast(bf16x8, p);
    }

    const int   pqmin = pos0 + w * 16;
    const int   pqmax = pqmin + 15;
    const int   posq  = pqmin + l15;
    const float sink2 = sinks[h] * 1.4426950408889634f;
    float mrun = sink2;
    float lrun = 1.0f;
    f32x4 o[8];
    #pragma unroll
    for (int g = 0; g < 8; ++g) o[g] = (f32x4){0.f, 0.f, 0.f, 0.f};

    for (int jt = jt0; jt <= jt1; jt += 64) {
        const int    blk    = btab[b * NBLK_ + (jt >> 7)];
        const size_t kgbase = (size_t)blk * (2 * BS_ * KVROW) + (size_t)(jt & 127) * KVROW + kh * D_;
        const size_t vgbase = kgbase + (size_t)BS_ * KVROW;

        __syncthreads();
        {
            const int kl = tid >> 2;
            const int cb = (tid & 3) * 64;
            const float* src = kv + kgbase + (size_t)kl * KVROW + (tid & 3) * 32;
            char* dst = (char*)Klds + kl * 256;
            #pragma unroll
            for (int i = 0; i < 4; ++i) {
                const float4v f0 = *reinterpret_cast<const float4v*>(src + i * 8);
                const float4v f1 = *reinterpret_cast<const float4v*>(src + i * 8 + 4);
                u32x4 p;
                p[0] = pk2(f0[0], f0[1]); p[1] = pk2(f0[2], f0[3]);
                p[2] = pk2(f1[1-1], f1[1]); p[3] = pk2(f1[2], f1[3]);
                *reinterpret_cast<u32x4*>(dst + ((cb + i * 16) ^ ((kl & 15) << 4))) = p;
            }
        }
        {
            const int db = tid & 31;
            #pragma unroll
            for (int half = 0; half < 2; ++half) {
                const int kb = (tid >> 5) + half * 8;
                const int k0 = kb * 4;
                const float* vsrc = kv + vgbase + (size_t)k0 * KVROW + db * 4;
                const float4v r0 = *reinterpret_cast<const float4v*>(vsrc);
                const float4v r1 = *reinterpret_cast<const float4v*>(vsrc + KVROW);
                const float4v r2 = *reinterpret_cast<const float4v*>(vsrc + 2 * KVROW);
                const float4v r3 = *reinterpret_cast<const float4v*>(vsrc + 3 * KVROW);
                #pragma unroll
                for (int dd = 0; dd < 4; ++dd) {
                    const int d    = db * 4 + dd;
                    const int g    = d >> 4;
                    const int slot = ((kb >> 1) & 3) * 16 + ((d & 15) ^ (g & 7));
                    const int elem = (g * 2 + (k0 >> 5)) * 512 + slot * 8 + (k0 & 7);
                    u32x2 wv;
                    wv[0] = pk2(r0[dd], r1[dd]);
                    wv[1] = pk2(r2[dd], r3[dd]);
                    *reinterpret_cast<u32x2*>(&Vlds[elem]) = wv;
                }
            }
        }
        __syncthreads();

        if (jt > pqmax || jt + 63 <= pqmin - win) continue;
        const bool edge = (jt + 63 > pqmin) || (jt <= pqmax - win);

        f32x4 sacc[4];
        #pragma unroll
        for (int g = 0; g < 4; ++g) sacc[g] = (f32x4){0.f, 0.f, 0.f, 0.f};
        #pragma unroll
        for (int g = 0; g < 4; ++g) {
            const char* krow = (const char*)Klds + (g * 16 + l15) * 256;
            const int   swz  = (l15 << 4);
            #pragma unroll
            for (int dc = 0; dc < 4; ++dc) {
                const bf16x8 a = *reinterpret_cast<const bf16x8*>(
                    krow + ((dc * 64 + lhi * 16) ^ swz));
                sacc[g] = __builtin_amdgcn_mfma_f32_16x16x32_bf16(a, qf[dc], sacc[g], 0, 0, 0);
            }
        }

        float sv[16];
        float mloc = -3e38f;
        if (edge) {
            #pragma unroll
            for (int g = 0; g < 4; ++g) {
                #pragma unroll
                for (int i = 0; i < 4; ++i) {
                    const int  kglob = jt + g * 16 + lhi * 4 + i;
                    const bool ok = (kglob <= posq) && (kglob > posq - win);
                    const float s = ok ? sacc[g][i] : -1e30f;
                    sv[g * 4 + i] = s;
                    mloc = fmaxf(mloc, s);
                }
            }
        } else {
            #pragma unroll
            for (int g = 0; g < 4; ++g) {
                #pragma unroll
                for (int i = 0; i < 4; ++i) {
                    sv[g * 4 + i] = sacc[g][i];
                    mloc = fmaxf(mloc, sacc[g][i]);
                }
            }
        }
        mloc = fmaxf(mloc, __shfl_xor(mloc, 16));
        mloc = fmaxf(mloc, __shfl_xor(mloc, 32));

        if (!__all(mloc <= mrun + 8.0f)) {
            const float mnew  = fmaxf(mrun, mloc);
            const float alpha = EXP2(mrun - mnew);
            lrun *= alpha;
            #pragma unroll
            for (int g = 0; g < 8; ++g) o[g] *= alpha;
            mrun = mnew;
        }

        float ps = 0.f;
        unsigned pw[8];
        #pragma unroll
        for (int t = 0; t < 8; ++t) {
            const float p0 = EXP2(sv[2 * t]     - mrun);
            const float p1 = EXP2(sv[2 * t + 1] - mrun);
            ps += p0 + p1;
            pw[t] = pk2(p0, p1);
        }
        ps += __shfl_xor(ps, 16);
        ps += __shfl_xor(ps, 32);
        lrun += ps;

        #pragma unroll
        for (int g = 0; g < 4; ++g) {
            u32x2 wv; wv[0] = pw[2 * g]; wv[1] = pw[2 * g + 1];
            *reinterpret_cast<u32x2*>(&Plds[w][l15 * PP + g * 16 + lhi * 4]) = wv;
        }

        #pragma unroll
        for (int kc = 0; kc < 2; ++kc) {
            const bf16x8 pf = *reinterpret_cast<const bf16x8*>(
                &Plds[w][l15 * PP + kc * 32 + lhi * 8]);
            #pragma unroll
            for (int g = 0; g < 8; ++g) {
                const bf16x8 vf = *reinterpret_cast<const bf16x8*>(
                    &Vlds[(g * 2 + kc) * 512 + (lhi * 16 + (l15 ^ (g & 7))) * 8]);
                o[g] = __builtin_amdgcn_mfma_f32_16x16x32_bf16(vf, pf, o[g], 0, 0, 0);
            }
        }
    }

    const float  inv   = 1.0f / lrun;
    const size_t obase = ((size_t)(b * Q_ + qr) * HQ_ + h) * D_;
    #pragma unroll
    for (int g = 0; g < 8; ++g) {
        float4v v;
        v[0] = o[g][0] * inv; v[1] = o[g][1] * inv;
        v[2] = o[g][2] * inv; v[3] = o[g][3] * inv;
        *reinterpret_cast<float4v*>(out + obase + g * 16 + lhi * 4) = v;
    }
}

extern "C" void kernel_launch(void* const* d_in, const int* in_sizes, int n_in,
                              void* d_out, int out_size, void* d_ws, size_t ws_size,
                              hipStream_t stream) {
    const float* q       = (const float*)d_in[0];
    const int*   btab    = (const int*)  d_in[1];
    const float* kv      = (const float*)d_in[2];
    const int*   seqused = (const int*)  d_in[3];
    const float* sinks   = (const float*)d_in[4];
    const int*   win     = (const int*)  d_in[5];
    float* out = (float*)d_out;

    const size_t wsK_elems = (size_t)NPHYS * 8 * BS_ * D_;   // 4.19M ushorts
    const size_t wsV_elems = (size_t)NPHYS * 8 * BS_ * D_;   // 4.19M ushorts
    const size_t need_bytes = (wsK_elems + wsV_elems) * 2;   // ~16.8 MB

    if (ws_size >= need_bytes) {
        unsigned short* wsK = (unsigned short*)d_ws;
        unsigned short* wsV = wsK + wsK_elems;
        swa_prepass<<<dim3(NPHYS * 8 * 2), dim3(256), 0, stream>>>(kv, wsK, wsV);
        swa_main<<<dim3(B_ * HQ_ * 16), dim3(256), 0, stream>>>(
            q, btab, seqused, sinks, win, wsK, wsV, out);
    } else {
        swa_fallback<<<dim3(B_ * HQ_ * 8), dim3(256), 0, stream>>>(
            q, btab, kv, seqused, sinks, win, out);
    }
}